// Round 1
// baseline (20743.315 us; speedup 1.0000x reference)
//
#include <hip/hip_runtime.h>
#include <math.h>

#define LATENT 16
#define NREP 10
#define NSTEPS 10
#define NTERMS 169   // 1 + 16 + 136 + 16
#define DT 0.01f

// One thread = one (n, r) trajectory. Block handles 256 consecutive n for a
// single replicate r (blockIdx.y). Masked coefficients (with DT folded in)
// staged in LDS; all lanes read the same row -> broadcast, conflict-free.
__global__ __launch_bounds__(256) void sindy_euler_kernel(
    const float* __restrict__ h_t,        // [N, 16]
    const float* __restrict__ coeff,      // [10, 169, 16]
    const float* __restrict__ mask,       // [10, 169, 16]
    float* __restrict__ out,              // [N, 10, 16]
    int N)
{
    __shared__ float Cs[NTERMS][LATENT];  // 169*16*4 = 10816 B

    const int r = blockIdx.y;
    {
        const float* cr = coeff + (size_t)r * NTERMS * LATENT;
        const float* mr = mask  + (size_t)r * NTERMS * LATENT;
        for (int i = threadIdx.x; i < NTERMS * LATENT; i += 256) {
            Cs[i / LATENT][i % LATENT] = cr[i] * mr[i] * DT;
        }
    }
    __syncthreads();

    const int n = blockIdx.x * 256 + threadIdx.x;
    if (n >= N) return;

    // Load h (16 floats = one 64B line per lane, 4x float4)
    float h[LATENT];
    {
        const float4* hp = reinterpret_cast<const float4*>(h_t + (size_t)n * LATENT);
        float4 a = hp[0], b = hp[1], c = hp[2], d = hp[3];
        h[0]=a.x; h[1]=a.y; h[2]=a.z; h[3]=a.w;
        h[4]=b.x; h[5]=b.y; h[6]=b.z; h[7]=b.w;
        h[8]=c.x; h[9]=c.y; h[10]=c.z; h[11]=c.w;
        h[12]=d.x; h[13]=d.y; h[14]=d.z; h[15]=d.w;
    }

    // 10 sequential Euler steps; step loop NOT unrolled (code size), body fully
    // unrolled so h[]/dh[] stay in registers (no dynamic reg indexing).
    for (int s = 0; s < NSTEPS; ++s) {
        float dh[LATENT];

        // term 0: ones
        #pragma unroll
        for (int d = 0; d < LATENT; ++d) dh[d] = Cs[0][d];

        // terms 1..16: linear z
        #pragma unroll
        for (int i = 0; i < LATENT; ++i) {
            #pragma unroll
            for (int d = 0; d < LATENT; ++d) dh[d] += h[i] * Cs[1 + i][d];
        }

        // terms 17..152: quadratic z_i*z_j, i<=j, np.triu_indices order
        {
            int l = 17;
            #pragma unroll
            for (int i = 0; i < LATENT; ++i) {
                #pragma unroll
                for (int j = i; j < LATENT; ++j) {
                    const float t = h[i] * h[j];
                    #pragma unroll
                    for (int d = 0; d < LATENT; ++d) dh[d] += t * Cs[l][d];
                    ++l;
                }
            }
        }

        // terms 153..168: sin(z)
        #pragma unroll
        for (int i = 0; i < LATENT; ++i) {
            const float t = __sinf(h[i]);
            #pragma unroll
            for (int d = 0; d < LATENT; ++d) dh[d] += t * Cs[153 + i][d];
        }

        // Euler update (DT already folded into Cs)
        #pragma unroll
        for (int d = 0; d < LATENT; ++d) h[d] += dh[d];
    }

    // out[n][r][d]: each lane writes one full 64B line (4x float4)
    float* op = out + ((size_t)n * NREP + r) * LATENT;
    float4* ov = reinterpret_cast<float4*>(op);
    ov[0] = make_float4(h[0], h[1], h[2], h[3]);
    ov[1] = make_float4(h[4], h[5], h[6], h[7]);
    ov[2] = make_float4(h[8], h[9], h[10], h[11]);
    ov[3] = make_float4(h[12], h[13], h[14], h[15]);
}

extern "C" void kernel_launch(void* const* d_in, const int* in_sizes, int n_in,
                              void* d_out, int out_size, void* d_ws, size_t ws_size,
                              hipStream_t stream) {
    const float* h_t   = (const float*)d_in[0];
    const float* coeff = (const float*)d_in[1];
    const float* mask  = (const float*)d_in[2];
    float* out = (float*)d_out;

    const int N = in_sizes[0] / LATENT;  // 50000
    dim3 grid((N + 255) / 256, NREP);
    dim3 block(256);
    sindy_euler_kernel<<<grid, block, 0, stream>>>(h_t, coeff, mask, out, N);
}

// Round 2
// 202.035 us; speedup vs baseline: 102.6720x; 102.6720x over previous
//
#include <hip/hip_runtime.h>
#include <hip/hip_bf16.h>
#include <math.h>

#define LATENT 16
#define NREP 10
#define NSTEPS 10
#define NTERMS 169          // 1 + 16 + 136 + 16
#define NCHUNK 12           // 12 x K=16 = 192 k-slots (169 real + 23 zero pad)
#define DT 0.01f

typedef __attribute__((ext_vector_type(8))) short short8;     // 8 bf16 (4 VGPRs)
typedef __attribute__((ext_vector_type(16))) float f32x16;    // MFMA 32x32 acc

struct Term { int type; int i; int j; };  // 0=one 1=lin 2=quad 3=sin 4=zero

__host__ __device__ constexpr Term term_of(int k) {
    if (k == 0)   return Term{0, 0, 0};
    if (k <= 16)  return Term{1, k - 1, 0};
    if (k <= 152) {                       // quad, np.triu_indices order
        int q = k - 17, i = 0;
        while (q >= LATENT - i) { q -= LATENT - i; ++i; }
        return Term{2, i, i + q};
    }
    if (k <= 168) return Term{3, k - 153, 0};
    return Term{4, 0, 0};
}

union Frag8 { short8 v; __hip_bfloat16 e[8]; };

template<int K>
__device__ __forceinline__ float theta_val(const float (&h)[LATENT]) {
    constexpr Term t = term_of(K);
    if constexpr (t.type == 0) return 1.0f;
    else if constexpr (t.type == 1) return h[t.i];
    else if constexpr (t.type == 2) return h[t.i] * h[t.j];
    else if constexpr (t.type == 3) return __sinf(h[t.i]);
    else return 0.0f;
}

template<int G, int C>
__device__ __forceinline__ short8 build_frag(const float (&h)[LATENT]) {
    Frag8 b;
    b.e[0] = __float2bfloat16(theta_val<C*16 + G*8 + 0>(h));
    b.e[1] = __float2bfloat16(theta_val<C*16 + G*8 + 1>(h));
    b.e[2] = __float2bfloat16(theta_val<C*16 + G*8 + 2>(h));
    b.e[3] = __float2bfloat16(theta_val<C*16 + G*8 + 3>(h));
    b.e[4] = __float2bfloat16(theta_val<C*16 + G*8 + 4>(h));
    b.e[5] = __float2bfloat16(theta_val<C*16 + G*8 + 5>(h));
    b.e[6] = __float2bfloat16(theta_val<C*16 + G*8 + 6>(h));
    b.e[7] = __float2bfloat16(theta_val<C*16 + G*8 + 7>(h));
    return b.v;
}

template<int G>
__device__ __forceinline__ void build_all(const float (&h)[LATENT], short8 (&bf)[NCHUNK]) {
    bf[0]  = build_frag<G, 0>(h);
    bf[1]  = build_frag<G, 1>(h);
    bf[2]  = build_frag<G, 2>(h);
    bf[3]  = build_frag<G, 3>(h);
    bf[4]  = build_frag<G, 4>(h);
    bf[5]  = build_frag<G, 5>(h);
    bf[6]  = build_frag<G, 6>(h);
    bf[7]  = build_frag<G, 7>(h);
    bf[8]  = build_frag<G, 8>(h);
    bf[9]  = build_frag<G, 9>(h);
    bf[10] = build_frag<G, 10>(h);
    bf[11] = build_frag<G, 11>(h);
}

__device__ __forceinline__ short cdt2bf(float c, float m) {
    return __hip_bfloat16_raw(__float2bfloat16(c * m * DT)).x;
}

// One wave = one (replicate r, 32-trajectory tile). D = (C_r*mask*DT)^T @ Theta^T
// via 12x mfma_f32_32x32x16_bf16. Trajectory = lane&31 (D column), k-half = lane>>5.
// h[16] fp32 replicated per lane (2 lanes/traj); dh crosses halves via shfl_xor(32).
__global__ __launch_bounds__(256) void sindy_mfma_kernel(
    const float* __restrict__ h_t,    // [N, 16]
    const float* __restrict__ coeff,  // [10, 169, 16]
    const float* __restrict__ mask,   // [10, 169, 16]
    float* __restrict__ out,          // [N, 10, 16]
    int N, int ntiles)
{
    const int lane = threadIdx.x & 63;
    const int wid  = blockIdx.x * 4 + (threadIdx.x >> 6);
    if (wid >= NREP * ntiles) return;
    const int r    = wid / ntiles;
    const int tile = wid % ntiles;

    const int col = lane & 31;   // trajectory within tile; also A-row (dim)
    const int hi  = lane >> 5;   // k-slot group

    // ---- A fragments (hoisted, constant over steps): A[row=dim][k] ----
    short8 af[NCHUNK];
    {
        const float* cr = coeff + (size_t)r * NTERMS * LATENT;
        const float* mr = mask  + (size_t)r * NTERMS * LATENT;
        #pragma unroll
        for (int c = 0; c < NCHUNK; ++c) {
            Frag8 a;
            #pragma unroll
            for (int j = 0; j < 8; ++j) {
                const int k = c * 16 + hi * 8 + j;
                float v = 0.0f;
                if (col < LATENT && k < NTERMS) {
                    const int idx = k * LATENT + col;
                    v = cr[idx] * mr[idx] * DT;
                }
                a.e[j] = __float2bfloat16(v);
            }
            af[c] = a.v;
        }
    }

    // ---- h for my trajectory ----
    const int n = tile * 32 + col;
    float h[LATENT];
    if (n < N) {
        const float4* hp = reinterpret_cast<const float4*>(h_t + (size_t)n * LATENT);
        float4 q0 = hp[0], q1 = hp[1], q2 = hp[2], q3 = hp[3];
        h[0]=q0.x;  h[1]=q0.y;  h[2]=q0.z;  h[3]=q0.w;
        h[4]=q1.x;  h[5]=q1.y;  h[6]=q1.z;  h[7]=q1.w;
        h[8]=q2.x;  h[9]=q2.y;  h[10]=q2.z; h[11]=q2.w;
        h[12]=q3.x; h[13]=q3.y; h[14]=q3.z; h[15]=q3.w;
    } else {
        #pragma unroll
        for (int d = 0; d < LATENT; ++d) h[d] = 0.0f;
    }

    // ---- 10 sequential Euler steps ----
    for (int s = 0; s < NSTEPS; ++s) {
        short8 bf[NCHUNK];
        if (hi == 0) build_all<0>(h, bf);
        else         build_all<1>(h, bf);

        f32x16 acc;
        #pragma unroll
        for (int i = 0; i < 16; ++i) acc[i] = 0.0f;
        #pragma unroll
        for (int c = 0; c < NCHUNK; ++c)
            acc = __builtin_amdgcn_mfma_f32_32x32x16_bf16(af[c], bf[c], acc, 0, 0, 0);

        // acc reg t (t<8) = dh[dim = (t&3) + 8*(t>>2) + 4*hi]; regs 8..15 are zero pad.
        float p[8];
        #pragma unroll
        for (int t = 0; t < 8; ++t) p[t] = __shfl_xor(acc[t], 32);

        if (hi == 0) {
            h[0]+=acc[0];  h[1]+=acc[1];  h[2]+=acc[2];  h[3]+=acc[3];
            h[8]+=acc[4];  h[9]+=acc[5];  h[10]+=acc[6]; h[11]+=acc[7];
            h[4]+=p[0];    h[5]+=p[1];    h[6]+=p[2];    h[7]+=p[3];
            h[12]+=p[4];   h[13]+=p[5];   h[14]+=p[6];   h[15]+=p[7];
        } else {
            h[4]+=acc[0];  h[5]+=acc[1];  h[6]+=acc[2];  h[7]+=acc[3];
            h[12]+=acc[4]; h[13]+=acc[5]; h[14]+=acc[6]; h[15]+=acc[7];
            h[0]+=p[0];    h[1]+=p[1];    h[2]+=p[2];    h[3]+=p[3];
            h[8]+=p[4];    h[9]+=p[5];    h[10]+=p[6];   h[11]+=p[7];
        }
    }

    // ---- store: each half writes its two float4 quarters of out[n][r][:] ----
    if (n < N) {
        float* op = out + ((size_t)n * NREP + r) * LATENT;
        if (hi == 0) {
            *reinterpret_cast<float4*>(op + 0) = make_float4(h[0], h[1], h[2], h[3]);
            *reinterpret_cast<float4*>(op + 8) = make_float4(h[8], h[9], h[10], h[11]);
        } else {
            *reinterpret_cast<float4*>(op + 4)  = make_float4(h[4], h[5], h[6], h[7]);
            *reinterpret_cast<float4*>(op + 12) = make_float4(h[12], h[13], h[14], h[15]);
        }
    }
}

extern "C" void kernel_launch(void* const* d_in, const int* in_sizes, int n_in,
                              void* d_out, int out_size, void* d_ws, size_t ws_size,
                              hipStream_t stream) {
    const float* h_t   = (const float*)d_in[0];
    const float* coeff = (const float*)d_in[1];
    const float* mask  = (const float*)d_in[2];
    float* out = (float*)d_out;

    const int N = in_sizes[0] / LATENT;          // 50000
    const int ntiles = (N + 31) / 32;            // 1563
    const int nwaves = NREP * ntiles;            // 15630
    const int nblocks = (nwaves + 3) / 4;

    sindy_mfma_kernel<<<dim3(nblocks), dim3(256), 0, stream>>>(
        h_t, coeff, mask, out, N, ntiles);
}